// Round 1
// baseline (775.852 us; speedup 1.0000x reference)
//
#include <hip/hip_runtime.h>
#include <math.h>

#define BB   1024
#define FIN  128
#define NOUT 10000
#define NK   16
#define NBLK 79     // ceil(10000/128)

// ---------------------------------------------------------------------------
// Kernel A: per-row input inverse-norm + margin params
// grid 1024 blocks x 64 threads (one wave per row)
__global__ void rowprep(const float* __restrict__ X, const float* __restrict__ factor,
                        float* __restrict__ xinv, float* __restrict__ fa_out,
                        float* __restrict__ thr_out) {
    int b = blockIdx.x;
    int lane = threadIdx.x;
    float v0 = X[b * FIN + lane];
    float v1 = X[b * FIN + 64 + lane];
    float s = v0 * v0 + v1 * v1;
    #pragma unroll
    for (int off = 32; off > 0; off >>= 1) s += __shfl_down(s, off);
    if (lane == 0) {
        float n = sqrtf(s);
        xinv[b] = 1.0f / fmaxf(n, 1e-12f);
        float fa = powf(1.5f, factor[b] * (1.0f / 12.0f)) * 0.5f;
        fa_out[b] = fa;
        thr_out[b] = (float)M_PI - fa;
    }
}

// ---------------------------------------------------------------------------
// Kernel B: per-(k,o) weight-column inverse-norm. Coalesced across o.
__global__ void wnorm(const float* __restrict__ W, float* __restrict__ winv) {
    int t = blockIdx.x * blockDim.x + threadIdx.x;
    if (t >= NK * NOUT) return;
    int k = t / NOUT;
    int o = t - k * NOUT;
    const float* p = W + (size_t)k * FIN * NOUT + o;
    float s = 0.0f;
    #pragma unroll 8
    for (int f = 0; f < FIN; f++) {
        float w = p[(size_t)f * NOUT];
        s += w * w;
    }
    winv[t] = 1.0f / fmaxf(sqrtf(s), 1e-12f);
}

// ---------------------------------------------------------------------------
// Kernel C: fused GEMM + max-over-k + partial online-softmax stats.
// Tile: 128 rows x 128 cols, 256 threads, 8x8 per-thread register blocking.
// LDS: xs[f][row] 64KB (transposed X tile) + ws[f][col] 16KB (W chunk) = 80KB
//  -> 2 blocks/CU. __launch_bounds__(256,2) caps VGPR at 256.
__global__ __launch_bounds__(256, 2) void gemm_stats(
    const float* __restrict__ X, const float* __restrict__ W,
    const int* __restrict__ label, const float* __restrict__ xinv,
    const float* __restrict__ winv, float2* __restrict__ partial,
    float* __restrict__ cosl) {
    __shared__ float xs[FIN * 128];   // xs[f*128 + row]
    __shared__ float ws[32 * 128];    // ws[f*128 + col]

    const int tid = threadIdx.x;
    const int tx = tid & 15;
    const int ty = tid >> 4;
    const int jb = blockIdx.x;        // col block 0..78
    const int by = blockIdx.y;        // row block 0..7
    const int r0 = by * 128;
    const int o0 = jb * 128;

    // ---- stage X tile transposed (once) ----
    #pragma unroll
    for (int it = 0; it < 16; it++) {
        int idx = it * 256 + tid;      // float4 index 0..4095
        int row = idx >> 5;            // 32 float4 per row
        int c4  = idx & 31;
        float4 v = *(const float4*)(X + (size_t)(r0 + row) * FIN + c4 * 4);
        xs[(c4 * 4 + 0) * 128 + row] = v.x;
        xs[(c4 * 4 + 1) * 128 + row] = v.y;
        xs[(c4 * 4 + 2) * 128 + row] = v.z;
        xs[(c4 * 4 + 3) * 128 + row] = v.w;
    }

    float maxv[8][8];
    #pragma unroll
    for (int i = 0; i < 8; i++)
        #pragma unroll
        for (int j = 0; j < 8; j++) maxv[i][j] = -INFINITY;

    for (int k = 0; k < NK; k++) {
        // per-k column inverse-norms (L2-resident, broadcast-friendly)
        float wv[8];
        #pragma unroll
        for (int j = 0; j < 8; j++) {
            int o = o0 + ((j < 4) ? tx * 4 + j : 64 + tx * 4 + (j - 4));
            wv[j] = (o < NOUT) ? winv[k * NOUT + o] : 0.0f;
        }
        float acc[8][8] = {};
        for (int fc = 0; fc < 4; fc++) {
            __syncthreads();   // previous chunk consumers done (also covers xs stage)
            // ---- stage W chunk: 32 f-rows x 128 cols ----
            #pragma unroll
            for (int it = 0; it < 4; it++) {
                int idx = it * 256 + tid;   // float4 idx 0..1023
                int f  = idx >> 5;
                int c4 = idx & 31;
                int o  = o0 + c4 * 4;
                float4 v = make_float4(0.f, 0.f, 0.f, 0.f);
                if (o < NOUT)
                    v = *(const float4*)(W + ((size_t)k * FIN + fc * 32 + f) * NOUT + o);
                *(float4*)(ws + f * 128 + c4 * 4) = v;
            }
            __syncthreads();
            for (int f = 0; f < 32; f++) {
                const float* xp = xs + (fc * 32 + f) * 128;
                const float* wp = ws + f * 128;
                float4 a0 = *(const float4*)(xp + ty * 4);
                float4 a1 = *(const float4*)(xp + 64 + ty * 4);
                float4 b0 = *(const float4*)(wp + tx * 4);
                float4 b1 = *(const float4*)(wp + 64 + tx * 4);
                float av[8] = {a0.x, a0.y, a0.z, a0.w, a1.x, a1.y, a1.z, a1.w};
                float bv[8] = {b0.x, b0.y, b0.z, b0.w, b1.x, b1.y, b1.z, b1.w};
                #pragma unroll
                for (int i = 0; i < 8; i++)
                    #pragma unroll
                    for (int j = 0; j < 8; j++)
                        acc[i][j] = fmaf(av[i], bv[j], acc[i][j]);
            }
        }
        // fold winv scale inside the max over k
        #pragma unroll
        for (int i = 0; i < 8; i++)
            #pragma unroll
            for (int j = 0; j < 8; j++)
                maxv[i][j] = fmaxf(maxv[i][j], acc[i][j] * wv[j]);
    }

    // ---- epilogue: per-row partial online-softmax stats (label col excluded) ----
    int rows[8]; float xi[8]; int lab[8];
    #pragma unroll
    for (int i = 0; i < 8; i++) {
        rows[i] = r0 + ((i < 4) ? ty * 4 + i : 64 + ty * 4 + (i - 4));
        xi[i] = xinv[rows[i]];
        lab[i] = label[rows[i]];
    }
    #pragma unroll
    for (int i = 0; i < 8; i++) {
        float m = -1e30f, s = 0.0f;
        #pragma unroll
        for (int j = 0; j < 8; j++) {
            int o = o0 + ((j < 4) ? tx * 4 + j : 64 + tx * 4 + (j - 4));
            if (o < NOUT) {
                float c = maxv[i][j] * xi[i];
                if (o == lab[i]) {
                    cosl[rows[i]] = c;   // unique writer across the whole grid row
                } else {
                    float l = 64.0f * fminf(fmaxf(c, -1.0f + 1e-6f), 1.0f - 1e-6f);
                    if (l > m) { s = s * __expf(m - l) + 1.0f; m = l; }
                    else       { s += __expf(l - m); }
                }
            }
        }
        // reduce across the 16 tx lanes (lane bits 0..3)
        #pragma unroll
        for (int off = 1; off <= 8; off <<= 1) {
            float m2 = __shfl_xor(m, off);
            float s2 = __shfl_xor(s, off);
            float M = fmaxf(m, m2);
            s = s * __expf(m - M) + s2 * __expf(m2 - M);
            m = M;
        }
        if (tx == 0) partial[(size_t)jb * BB + rows[i]] = make_float2(m, s);
    }
}

// ---------------------------------------------------------------------------
// Kernel D: combine partials per row, apply margin to label logit, reduce to
// (cls_loss, prec1). One block, 1024 threads (one per row).
__global__ void finalize(const float2* __restrict__ partial, const float* __restrict__ cosl,
                         const float* __restrict__ fa, const float* __restrict__ thr,
                         float* __restrict__ out) {
    int b = threadIdx.x;
    float m = -1e30f, s = 0.0f;
    for (int j = 0; j < NBLK; j++) {
        float2 p = partial[(size_t)j * BB + b];
        float M = fmaxf(m, p.x);
        s = s * __expf(m - M) + p.y * __expf(p.x - M);
        m = M;
    }
    // label logit with disguise-adaptive margin
    float c = fminf(fmaxf(cosl[b], -1.0f + 1e-6f), 1.0f - 1e-6f);
    float theta = acosf(c);
    float ll = (theta > thr[b]) ? 64.0f * c : 64.0f * cosf(theta + fa[b]);
    float M = fmaxf(m, ll);
    float S = s * __expf(m - M) + __expf(ll - M);
    float loss = M + logf(S) - ll;            // = -(log_softmax at label)
    float corr = (ll > m) ? 100.0f : 0.0f;    // pred==label iff label logit beats all others

    __shared__ float sl[1024];
    __shared__ float sc[1024];
    sl[b] = loss;
    sc[b] = corr;
    __syncthreads();
    for (int st = 512; st > 0; st >>= 1) {
        if (b < st) { sl[b] += sl[b + st]; sc[b] += sc[b + st]; }
        __syncthreads();
    }
    if (b == 0) {
        out[0] = sl[0] * (1.0f / 1024.0f);
        out[1] = sc[0] * (1.0f / 1024.0f);
    }
}

// ---------------------------------------------------------------------------
extern "C" void kernel_launch(void* const* d_in, const int* in_sizes, int n_in,
                              void* d_out, int out_size, void* d_ws, size_t ws_size,
                              hipStream_t stream) {
    const float* X      = (const float*)d_in[0];   // 1024 x 128
    const float* factor = (const float*)d_in[1];   // 1024
    const int*   label  = (const int*)d_in[2];     // 1024
    const float* W      = (const float*)d_in[3];   // 16 x 128 x 10000
    float* out = (float*)d_out;
    float* ws  = (float*)d_ws;

    // workspace layout (floats): total ~1.25 MB
    float*  xinv  = ws;                       // 1024
    float*  fa    = ws + 1024;                // 1024
    float*  thr   = ws + 2048;                // 1024
    float*  winv  = ws + 3072;                // 160000
    float*  cosl  = ws + 3072 + 160000;       // 1024  (offset 163072)
    float2* partial = (float2*)(ws + 164096); // 79*1024 float2 (8B-aligned: 164096*4 % 8 == 0)

    rowprep<<<BB, 64, 0, stream>>>(X, factor, xinv, fa, thr);
    wnorm<<<(NK * NOUT + 255) / 256, 256, 0, stream>>>(W, winv);
    dim3 g(NBLK, BB / 128);
    gemm_stats<<<g, 256, 0, stream>>>(X, W, label, xinv, winv, partial, cosl);
    finalize<<<1, BB, 0, stream>>>(partial, cosl, fa, thr, out);
}

// Round 2
// 433.172 us; speedup vs baseline: 1.7911x; 1.7911x over previous
//
#include <hip/hip_runtime.h>
#include <hip/hip_bf16.h>
#include <math.h>

#define BB    1024
#define FIN   128
#define NOUT  10000
#define NK    16
#define NBLK  79          // ceil(10000/128)
#define NPART (NBLK * 2)  // two waves per block write per-row partials
#define LDX   136         // LDS row stride in bf16 elements (128 + 8 pad)

typedef __attribute__((ext_vector_type(8))) short short8;
typedef __attribute__((ext_vector_type(4))) float floatx4;

// pack two fp32 -> two bf16 (RNE) in one uint
__device__ __forceinline__ unsigned packbf(float a, float b) {
    __hip_bfloat162 h = __float22bfloat162_rn(make_float2(a, b));
    union { __hip_bfloat162 h2; unsigned u; } v;
    v.h2 = h;
    return v.u;
}

// ---------------------------------------------------------------------------
// Kernel A: per-row input inverse-norm + margin params
__global__ void rowprep(const float* __restrict__ X, const float* __restrict__ factor,
                        float* __restrict__ xinv, float* __restrict__ fa_out,
                        float* __restrict__ thr_out) {
    int b = blockIdx.x;
    int lane = threadIdx.x;
    float v0 = X[b * FIN + lane];
    float v1 = X[b * FIN + 64 + lane];
    float s = v0 * v0 + v1 * v1;
    #pragma unroll
    for (int off = 32; off > 0; off >>= 1) s += __shfl_down(s, off);
    if (lane == 0) {
        float n = sqrtf(s);
        xinv[b] = 1.0f / fmaxf(n, 1e-12f);
        float fa = powf(1.5f, factor[b] * (1.0f / 12.0f)) * 0.5f;
        fa_out[b] = fa;
        thr_out[b] = (float)M_PI - fa;
    }
}

// ---------------------------------------------------------------------------
// Kernel B: MFMA GEMM + max-over-k + partial online-softmax stats.
// 128x128 tile, 256 threads = 4 waves (2x2 grid of 64x64 wave tiles).
// A (X, raw bf16) fragments held in registers across all 16 sub-centers.
// W staged per-k: fp32 load -> inline sumsq (column norms) -> bf16 ->
// transposed LDS wt[o][f]. Norm scales folded as fp32 scalars after MFMA.
__global__ __launch_bounds__(256, 2) void gemm_stats(
    const float* __restrict__ X, const float* __restrict__ W,
    const int* __restrict__ label, const float* __restrict__ xinv,
    float2* __restrict__ partial, float* __restrict__ cosl) {

    __shared__ short xs[128 * LDX];   // X tile, bf16 [row][k]
    __shared__ short wt[128 * LDX];   // W_k tile transposed, bf16 [o][f]
    __shared__ float sqs[128][2];     // per-column sumsq halves

    const int tid  = threadIdx.x;
    const int lane = tid & 63;
    const int w    = tid >> 6;
    const int l15  = lane & 15;
    const int q    = lane >> 4;
    const int wm   = w & 1;           // wave row (m) half
    const int wn   = w >> 1;          // wave col (n) half
    const int jb   = blockIdx.x;
    const int r0   = blockIdx.y * 128;
    const int o0   = jb * 128;

    // ---- stage raw X tile as bf16, row-major [row][k] ----
    #pragma unroll
    for (int it = 0; it < 16; it++) {
        int idx = it * 256 + tid;          // float4 index 0..4095
        int row = idx >> 5;
        int c4  = idx & 31;
        const float4 v = *(const float4*)(X + (size_t)(r0 + row) * FIN + c4 * 4);
        uint2 p;
        p.x = packbf(v.x, v.y);
        p.y = packbf(v.z, v.w);
        *(uint2*)(xs + row * LDX + c4 * 4) = p;
    }
    __syncthreads();

    // ---- A fragments -> registers (k-invariant across sub-centers) ----
    // A[m = l15][k = q*8 + j], m-tile mt, K-chunk kk
    short8 af[4][4];
    #pragma unroll
    for (int mt = 0; mt < 4; mt++)
        #pragma unroll
        for (int kk = 0; kk < 4; kk++)
            af[mt][kk] = *(const short8*)(xs + (wm * 64 + mt * 16 + l15) * LDX + kk * 32 + q * 8);

    floatx4 maxv[4][4];
    #pragma unroll
    for (int mt = 0; mt < 4; mt++)
        #pragma unroll
        for (int nt = 0; nt < 4; nt++)
            #pragma unroll
            for (int r = 0; r < 4; r++)
                maxv[mt][nt][r] = -INFINITY;

    // staging role: wave (w&1) -> o half, (w>>1) -> f half
    const int st_o = (w & 1) * 64 + lane;  // 0..127
    const int st_f = (w >> 1) * 64;        // 0 or 64
    const int go   = o0 + st_o;
    const bool ov  = go < NOUT;

    for (int k = 0; k < NK; k++) {
        __syncthreads();   // previous wt consumers done
        // ---- stage W_k^T: 64 f-rows per lane, pack 4 at a time ----
        const float* Wk = W + ((size_t)k * FIN + st_f) * NOUT + go;
        float sq = 0.f;
        #pragma unroll
        for (int g = 0; g < 16; g++) {
            float a0 = 0.f, a1 = 0.f, a2 = 0.f, a3 = 0.f;
            if (ov) {
                a0 = Wk[(size_t)(g * 4 + 0) * NOUT];
                a1 = Wk[(size_t)(g * 4 + 1) * NOUT];
                a2 = Wk[(size_t)(g * 4 + 2) * NOUT];
                a3 = Wk[(size_t)(g * 4 + 3) * NOUT];
            }
            sq = fmaf(a0, a0, sq); sq = fmaf(a1, a1, sq);
            sq = fmaf(a2, a2, sq); sq = fmaf(a3, a3, sq);
            uint2 p;
            p.x = packbf(a0, a1);
            p.y = packbf(a2, a3);
            *(uint2*)(wt + st_o * LDX + st_f + g * 4) = p;
        }
        sqs[st_o][w >> 1] = sq;
        __syncthreads();

        // per-column inverse norms for this wave's 4 n-tiles (fp32)
        float wv[4];
        #pragma unroll
        for (int nt = 0; nt < 4; nt++) {
            int col = wn * 64 + nt * 16 + l15;
            float n = sqrtf(sqs[col][0] + sqs[col][1]);
            wv[nt] = 1.0f / fmaxf(n, 1e-12f);
        }

        // ---- MFMA: 64 per wave per k ----
        floatx4 acc[4][4];
        #pragma unroll
        for (int mt = 0; mt < 4; mt++)
            #pragma unroll
            for (int nt = 0; nt < 4; nt++)
                acc[mt][nt] = (floatx4){0.f, 0.f, 0.f, 0.f};

        #pragma unroll
        for (int kk = 0; kk < 4; kk++) {
            short8 bf[4];
            #pragma unroll
            for (int nt = 0; nt < 4; nt++)
                bf[nt] = *(const short8*)(wt + (wn * 64 + nt * 16 + l15) * LDX + kk * 32 + q * 8);
            #pragma unroll
            for (int mt = 0; mt < 4; mt++)
                #pragma unroll
                for (int nt = 0; nt < 4; nt++)
                    acc[mt][nt] = __builtin_amdgcn_mfma_f32_16x16x32_bf16(
                        af[mt][kk], bf[nt], acc[mt][nt], 0, 0, 0);
        }

        // fold column norm + max over sub-centers
        #pragma unroll
        for (int mt = 0; mt < 4; mt++)
            #pragma unroll
            for (int nt = 0; nt < 4; nt++)
                #pragma unroll
                for (int r = 0; r < 4; r++)
                    maxv[mt][nt][r] = fmaxf(maxv[mt][nt][r], acc[mt][nt][r] * wv[nt]);
    }

    // ---- epilogue: per-row partial online-softmax (label col excluded) ----
    // C/D layout: row = q*4 + reg, col = l15 (per 16x16 tile)
    #pragma unroll
    for (int mt = 0; mt < 4; mt++) {
        #pragma unroll
        for (int rr = 0; rr < 4; rr++) {
            int row = r0 + wm * 64 + mt * 16 + q * 4 + rr;
            float xi = xinv[row];
            int lb = label[row];
            float m = -1e30f, s = 0.f;
            #pragma unroll
            for (int nt = 0; nt < 4; nt++) {
                int o = o0 + wn * 64 + nt * 16 + l15;
                if (o < NOUT) {
                    float c = maxv[mt][nt][rr] * xi;
                    if (o == lb) {
                        cosl[row] = c;   // unique writer grid-wide
                    } else {
                        float l = 64.0f * fminf(fmaxf(c, -1.0f + 1e-6f), 1.0f - 1e-6f);
                        if (l > m) { s = s * __expf(m - l) + 1.0f; m = l; }
                        else       { s += __expf(l - m); }
                    }
                }
            }
            // reduce across the 16 lanes of this quad (lane bits 0..3)
            #pragma unroll
            for (int off = 1; off <= 8; off <<= 1) {
                float m2 = __shfl_xor(m, off);
                float s2 = __shfl_xor(s, off);
                float M = fmaxf(m, m2);
                s = s * __expf(m - M) + s2 * __expf(m2 - M);
                m = M;
            }
            if (l15 == 0) partial[(size_t)(jb * 2 + wn) * BB + row] = make_float2(m, s);
        }
    }
}

// ---------------------------------------------------------------------------
// Kernel C: combine partials per row, apply margin to label logit, reduce.
__global__ void finalize(const float2* __restrict__ partial, const float* __restrict__ cosl,
                         const float* __restrict__ fa, const float* __restrict__ thr,
                         float* __restrict__ out) {
    int b = threadIdx.x;
    float m = -1e30f, s = 0.0f;
    for (int j = 0; j < NPART; j++) {
        float2 p = partial[(size_t)j * BB + b];
        float M = fmaxf(m, p.x);
        s = s * __expf(m - M) + p.y * __expf(p.x - M);
        m = M;
    }
    float c = fminf(fmaxf(cosl[b], -1.0f + 1e-6f), 1.0f - 1e-6f);
    float theta = acosf(c);
    float ll = (theta > thr[b]) ? 64.0f * c : 64.0f * cosf(theta + fa[b]);
    float M = fmaxf(m, ll);
    float S = s * __expf(m - M) + __expf(ll - M);
    float loss = M + logf(S) - ll;
    float corr = (ll > m) ? 100.0f : 0.0f;

    __shared__ float sl[1024];
    __shared__ float sc[1024];
    sl[b] = loss;
    sc[b] = corr;
    __syncthreads();
    for (int st = 512; st > 0; st >>= 1) {
        if (b < st) { sl[b] += sl[b + st]; sc[b] += sc[b + st]; }
        __syncthreads();
    }
    if (b == 0) {
        out[0] = sl[0] * (1.0f / 1024.0f);
        out[1] = sc[0] * (1.0f / 1024.0f);
    }
}

// ---------------------------------------------------------------------------
extern "C" void kernel_launch(void* const* d_in, const int* in_sizes, int n_in,
                              void* d_out, int out_size, void* d_ws, size_t ws_size,
                              hipStream_t stream) {
    const float* X      = (const float*)d_in[0];   // 1024 x 128
    const float* factor = (const float*)d_in[1];   // 1024
    const int*   label  = (const int*)d_in[2];     // 1024
    const float* W      = (const float*)d_in[3];   // 16 x 128 x 10000
    float* out = (float*)d_out;
    float* ws  = (float*)d_ws;

    // workspace layout (floats): 4096 + 2*158*1024 = 327680 floats (~1.31 MB)
    float*  xinv = ws;                   // 1024
    float*  fa   = ws + 1024;            // 1024
    float*  thr  = ws + 2048;            // 1024
    float*  cosl = ws + 3072;            // 1024
    float2* partial = (float2*)(ws + 4096); // NPART x 1024 float2

    rowprep<<<BB, 64, 0, stream>>>(X, factor, xinv, fa, thr);
    dim3 g(NBLK, BB / 128);
    gemm_stats<<<g, 256, 0, stream>>>(X, W, label, xinv, partial, cosl);
    finalize<<<1, BB, 0, stream>>>(partial, cosl, fa, thr, out);
}

// Round 3
// 275.885 us; speedup vs baseline: 2.8122x; 1.5701x over previous
//
#include <hip/hip_runtime.h>
#include <hip/hip_bf16.h>
#include <math.h>

#define BB    1024
#define FIN   128
#define NOUT  10000
#define NK    16
#define NBLK  79          // ceil(10000/128)
#define NPART (NBLK * 2)  // two waves per block write per-row partials
#define LDX   136         // LDS row stride in bf16 elems (16B-aligned rows, 2-way-free b128 reads)

typedef __attribute__((ext_vector_type(8))) short short8;
typedef __attribute__((ext_vector_type(4))) float floatx4;

// pack two fp32 -> two bf16 (RNE) in one uint
__device__ __forceinline__ unsigned packbf(float a, float b) {
    __hip_bfloat162 h = __float22bfloat162_rn(make_float2(a, b));
    union { __hip_bfloat162 h2; unsigned u; } v;
    v.h2 = h;
    return v.u;
}

// ---------------------------------------------------------------------------
// Kernel A: per-row input inverse-norm + margin params
__global__ void rowprep(const float* __restrict__ X, const float* __restrict__ factor,
                        float* __restrict__ xinv, float* __restrict__ fa_out,
                        float* __restrict__ thr_out) {
    int b = blockIdx.x;
    int lane = threadIdx.x;
    float v0 = X[b * FIN + lane];
    float v1 = X[b * FIN + 64 + lane];
    float s = v0 * v0 + v1 * v1;
    #pragma unroll
    for (int off = 32; off > 0; off >>= 1) s += __shfl_down(s, off);
    if (lane == 0) {
        float n = sqrtf(s);
        xinv[b] = 1.0f / fmaxf(n, 1e-12f);
        float fa = powf(1.5f, factor[b] * (1.0f / 12.0f)) * 0.5f;
        fa_out[b] = fa;
        thr_out[b] = (float)M_PI - fa;
    }
}

// ---------------------------------------------------------------------------
// Kernel B: MFMA GEMM + max-over-k + partial online-softmax stats.
// Software-pipelined k-loop: W(k+1) prefetched into VGPRs before MFMA(k).
// Block decode puts the 8 row-blocks sharing a jb strip on ids == (mod 8)
// within a 64-id window -> same XCD (round-robin heuristic), concurrent.
__global__ __launch_bounds__(256, 2) void gemm_stats(
    const float* __restrict__ X, const float* __restrict__ W,
    const int* __restrict__ label, const float* __restrict__ xinv,
    float2* __restrict__ partial, float* __restrict__ cosl) {

    __shared__ short xs[128 * LDX];   // X tile, bf16 [row][k]
    __shared__ short wt[128 * LDX];   // W_k tile transposed, bf16 [o][f]
    __shared__ float sqs[128][2];     // per-column sumsq halves

    const int tid  = threadIdx.x;
    const int lane = tid & 63;
    const int w    = tid >> 6;
    const int l15  = lane & 15;
    const int q    = lane >> 4;
    const int wm   = w & 1;           // wave row (m) half
    const int wn   = w >> 1;          // wave col (n) half

    // XCD-aware decode: ids {group*64 + y*8 + xcd} -> jb = group*8+xcd
    const int id    = blockIdx.x;
    const int group = id >> 6;
    const int sub   = id & 63;
    const int jb    = group * 8 + (sub & 7);
    const int y     = sub >> 3;
    if (jb >= NBLK) return;
    const int r0 = y * 128;
    const int o0 = jb * 128;

    // ---- stage raw X tile as bf16, row-major [row][k] ----
    #pragma unroll
    for (int it = 0; it < 16; it++) {
        int idx = it * 256 + tid;          // float4 index 0..4095
        int row = idx >> 5;
        int c4  = idx & 31;
        const float4 v = *(const float4*)(X + (size_t)(r0 + row) * FIN + c4 * 4);
        uint2 p;
        p.x = packbf(v.x, v.y);
        p.y = packbf(v.z, v.w);
        *(uint2*)(xs + row * LDX + c4 * 4) = p;
    }

    // staging role: wave (w&1) -> o half, (w>>1) -> f half
    const int st_o = (w & 1) * 64 + lane;  // 0..127
    const int st_f = (w >> 1) * 64;        // 0 or 64
    const int st_h = w >> 1;
    const int go   = o0 + st_o;
    const bool ov  = go < NOUT;

    // ---- prefetch W(k=0) into registers (overlaps X-stage sync) ----
    float rw[64];
    {
        const float* Wp = W + (size_t)st_f * NOUT + go;
        #pragma unroll
        for (int g = 0; g < 16; g++)
            #pragma unroll
            for (int c = 0; c < 4; c++)
                rw[g * 4 + c] = ov ? Wp[(size_t)(g * 4 + c) * NOUT] : 0.0f;
    }

    __syncthreads();

    // ---- A fragments -> registers (k-invariant across sub-centers) ----
    short8 af[4][4];
    #pragma unroll
    for (int mt = 0; mt < 4; mt++)
        #pragma unroll
        for (int kk = 0; kk < 4; kk++)
            af[mt][kk] = *(const short8*)(xs + (wm * 64 + mt * 16 + l15) * LDX + kk * 32 + q * 8);

    floatx4 maxv[4][4];
    #pragma unroll
    for (int mt = 0; mt < 4; mt++)
        #pragma unroll
        for (int nt = 0; nt < 4; nt++)
            #pragma unroll
            for (int r = 0; r < 4; r++)
                maxv[mt][nt][r] = -INFINITY;

    for (int k = 0; k < NK; k++) {
        // ---- pack + sumsq from prefetched rw ----
        float sq = 0.0f;
        uint2 pk[16];
        #pragma unroll
        for (int g = 0; g < 16; g++) {
            float a0 = rw[g * 4 + 0], a1 = rw[g * 4 + 1];
            float a2 = rw[g * 4 + 2], a3 = rw[g * 4 + 3];
            sq = fmaf(a0, a0, sq); sq = fmaf(a1, a1, sq);
            sq = fmaf(a2, a2, sq); sq = fmaf(a3, a3, sq);
            pk[g].x = packbf(a0, a1);
            pk[g].y = packbf(a2, a3);
        }
        __syncthreads();   // MFMA(k-1) consumers of wt done
        #pragma unroll
        for (int g = 0; g < 16; g++)
            *(uint2*)(wt + st_o * LDX + st_f + g * 4) = pk[g];
        sqs[st_o][st_h] = sq;
        __syncthreads();

        // ---- issue W(k+1) prefetch: latency covered by wv + MFMA + fold ----
        if (k < NK - 1) {
            const float* Wn = W + ((size_t)(k + 1) * FIN + st_f) * NOUT + go;
            #pragma unroll
            for (int g = 0; g < 16; g++)
                #pragma unroll
                for (int c = 0; c < 4; c++)
                    rw[g * 4 + c] = ov ? Wn[(size_t)(g * 4 + c) * NOUT] : 0.0f;
        }

        // per-column inverse norms for this wave's 4 n-tiles (fp32)
        float wv[4];
        #pragma unroll
        for (int nt = 0; nt < 4; nt++) {
            int col = wn * 64 + nt * 16 + l15;
            wv[nt] = 1.0f / fmaxf(sqrtf(sqs[col][0] + sqs[col][1]), 1e-12f);
        }

        // ---- MFMA in two nt-halves (acc = 32 VGPR instead of 64) ----
        #pragma unroll
        for (int h = 0; h < 2; h++) {
            floatx4 acc[4][2];
            #pragma unroll
            for (int mt = 0; mt < 4; mt++) {
                acc[mt][0] = (floatx4){0.f, 0.f, 0.f, 0.f};
                acc[mt][1] = (floatx4){0.f, 0.f, 0.f, 0.f};
            }
            #pragma unroll
            for (int kk = 0; kk < 4; kk++) {
                short8 bf0 = *(const short8*)(wt + (wn * 64 + (h * 2 + 0) * 16 + l15) * LDX + kk * 32 + q * 8);
                short8 bf1 = *(const short8*)(wt + (wn * 64 + (h * 2 + 1) * 16 + l15) * LDX + kk * 32 + q * 8);
                #pragma unroll
                for (int mt = 0; mt < 4; mt++) {
                    acc[mt][0] = __builtin_amdgcn_mfma_f32_16x16x32_bf16(af[mt][kk], bf0, acc[mt][0], 0, 0, 0);
                    acc[mt][1] = __builtin_amdgcn_mfma_f32_16x16x32_bf16(af[mt][kk], bf1, acc[mt][1], 0, 0, 0);
                }
            }
            #pragma unroll
            for (int mt = 0; mt < 4; mt++)
                #pragma unroll
                for (int n2 = 0; n2 < 2; n2++)
                    #pragma unroll
                    for (int r = 0; r < 4; r++)
                        maxv[mt][h * 2 + n2][r] =
                            fmaxf(maxv[mt][h * 2 + n2][r], acc[mt][n2][r] * wv[h * 2 + n2]);
        }
    }

    // ---- epilogue: per-row partial online-softmax (label col excluded) ----
    // C/D layout: row = q*4 + reg, col = l15 (per 16x16 tile)
    #pragma unroll
    for (int mt = 0; mt < 4; mt++) {
        #pragma unroll
        for (int rr = 0; rr < 4; rr++) {
            int row = r0 + wm * 64 + mt * 16 + q * 4 + rr;
            float xi = xinv[row];
            int lb = label[row];
            float m = -1e30f, s = 0.f;
            #pragma unroll
            for (int nt = 0; nt < 4; nt++) {
                int o = o0 + wn * 64 + nt * 16 + l15;
                if (o < NOUT) {
                    float c = maxv[mt][nt][rr] * xi;
                    if (o == lb) {
                        cosl[row] = c;   // unique writer grid-wide
                    } else {
                        float l = 64.0f * fminf(fmaxf(c, -1.0f + 1e-6f), 1.0f - 1e-6f);
                        if (l > m) { s = s * __expf(m - l) + 1.0f; m = l; }
                        else       { s += __expf(l - m); }
                    }
                }
            }
            #pragma unroll
            for (int off = 1; off <= 8; off <<= 1) {
                float m2 = __shfl_xor(m, off);
                float s2 = __shfl_xor(s, off);
                float M = fmaxf(m, m2);
                s = s * __expf(m - M) + s2 * __expf(m2 - M);
                m = M;
            }
            if (l15 == 0) partial[(size_t)row * NPART + jb * 2 + wn] = make_float2(m, s);
        }
    }
}

// ---------------------------------------------------------------------------
// Kernel C: one wave per row (256 blocks x 4 waves), coalesced row-major
// partials, shuffle-combine, margin on label logit, atomic scalar reduce.
__global__ void finalize(const float2* __restrict__ partial, const float* __restrict__ cosl,
                         const float* __restrict__ fa, const float* __restrict__ thr,
                         float* __restrict__ out) {
    int w = threadIdx.x >> 6;
    int lane = threadIdx.x & 63;
    int b = blockIdx.x * 4 + w;
    float m = -1e30f, s = 0.0f;
    for (int j = lane; j < NPART; j += 64) {
        float2 p = partial[(size_t)b * NPART + j];
        float M = fmaxf(m, p.x);
        s = s * __expf(m - M) + p.y * __expf(p.x - M);
        m = M;
    }
    #pragma unroll
    for (int off = 1; off < 64; off <<= 1) {
        float m2 = __shfl_xor(m, off);
        float s2 = __shfl_xor(s, off);
        float M = fmaxf(m, m2);
        s = s * __expf(m - M) + s2 * __expf(m2 - M);
        m = M;
    }
    if (lane == 0) {
        float c = fminf(fmaxf(cosl[b], -1.0f + 1e-6f), 1.0f - 1e-6f);
        float theta = acosf(c);
        float ll = (theta > thr[b]) ? 64.0f * c : 64.0f * cosf(theta + fa[b]);
        float M = fmaxf(m, ll);
        float S = s * __expf(m - M) + __expf(ll - M);
        atomicAdd(out,     (M + logf(S) - ll) * (1.0f / 1024.0f));
        atomicAdd(out + 1, (ll > m) ? (100.0f / 1024.0f) : 0.0f);
    }
}

// ---------------------------------------------------------------------------
extern "C" void kernel_launch(void* const* d_in, const int* in_sizes, int n_in,
                              void* d_out, int out_size, void* d_ws, size_t ws_size,
                              hipStream_t stream) {
    const float* X      = (const float*)d_in[0];   // 1024 x 128
    const float* factor = (const float*)d_in[1];   // 1024
    const int*   label  = (const int*)d_in[2];     // 1024
    const float* W      = (const float*)d_in[3];   // 16 x 128 x 10000
    float* out = (float*)d_out;
    float* ws  = (float*)d_ws;

    float*  xinv = ws;                      // 1024
    float*  fa   = ws + 1024;               // 1024
    float*  thr  = ws + 2048;               // 1024
    float*  cosl = ws + 3072;               // 1024
    float2* partial = (float2*)(ws + 4096); // 1024 x NPART float2 (~1.3 MB)

    hipMemsetAsync(out, 0, 2 * sizeof(float), stream);
    rowprep<<<BB, 64, 0, stream>>>(X, factor, xinv, fa, thr);
    gemm_stats<<<640, 256, 0, stream>>>(X, W, label, xinv, partial, cosl);
    finalize<<<BB / 4, 256, 0, stream>>>(partial, cosl, fa, thr, out);
}

// Round 4
// 222.594 us; speedup vs baseline: 3.4855x; 1.2394x over previous
//
#include <hip/hip_runtime.h>
#include <hip/hip_bf16.h>
#include <math.h>

#define BB    1024
#define FIN   128
#define NOUT  10000
#define NK    16
#define NBLK  79          // ceil(10000/128)
#define NPART (NBLK * 2)
#define OPAD  10112       // 79*128 padded column count
#define LDX   136         // LDS stride (shorts) for the X tile

typedef __attribute__((ext_vector_type(8))) short short8;
typedef __attribute__((ext_vector_type(4))) float floatx4;

// pack two fp32 -> two bf16 (RNE) in one uint
__device__ __forceinline__ unsigned packbf(float a, float b) {
    __hip_bfloat162 h = __float22bfloat162_rn(make_float2(a, b));
    union { __hip_bfloat162 h2; unsigned u; } v;
    v.h2 = h;
    return v.u;
}

// async global->LDS, 16B per lane. lds ptr is wave-uniform base; HW adds lane*16.
__device__ __forceinline__ void async16(const void* g, void* l) {
    __builtin_amdgcn_global_load_lds(
        (const __attribute__((address_space(1))) unsigned int*)g,
        (__attribute__((address_space(3))) unsigned int*)l, 16, 0, 0);
}

// ---------------------------------------------------------------------------
// Kernel A: per-row input inverse-norm + margin params
__global__ void rowprep(const float* __restrict__ X, const float* __restrict__ factor,
                        float* __restrict__ xinv, float* __restrict__ fa_out,
                        float* __restrict__ thr_out) {
    int b = blockIdx.x;
    int lane = threadIdx.x;
    float v0 = X[b * FIN + lane];
    float v1 = X[b * FIN + 64 + lane];
    float s = v0 * v0 + v1 * v1;
    #pragma unroll
    for (int off = 32; off > 0; off >>= 1) s += __shfl_down(s, off);
    if (lane == 0) {
        float n = sqrtf(s);
        xinv[b] = 1.0f / fmaxf(n, 1e-12f);
        float fa = powf(1.5f, factor[b] * (1.0f / 12.0f)) * 0.5f;
        fa_out[b] = fa;
        thr_out[b] = (float)M_PI - fa;
    }
}

// ---------------------------------------------------------------------------
// Kernel W: one-time W conversion. Output layout: per (k,o) column, 256 B =
// 16 chunks of 8 bf16 (pre-normalized w*winv); true chunk c stored at
// position c ^ (o&15) so gemm's b128 reads hit uniform 8 words/bank.
// Threads: one per (k,o) over the padded o range; pad columns -> zeros.
__global__ void wconv(const float* __restrict__ W, unsigned char* __restrict__ Wbf) {
    int t = blockIdx.x * 256 + threadIdx.x;      // 0 .. 16*OPAD-1
    int k = t / OPAD;
    int o = t - k * OPAD;
    const bool ok = o < NOUT;
    const float* p = W + (size_t)k * FIN * NOUT + o;
    float v[FIN];
    float s = 0.0f;
    #pragma unroll
    for (int f = 0; f < FIN; f++) {
        float x = ok ? p[(size_t)f * NOUT] : 0.0f;
        v[f] = x;
        s = fmaf(x, x, s);
    }
    float wi = ok ? (1.0f / fmaxf(sqrtf(s), 1e-12f)) : 0.0f;
    unsigned char* dst = Wbf + (size_t)t * 256;
    #pragma unroll
    for (int c = 0; c < 16; c++) {
        uint4 u;
        u.x = packbf(v[c * 8 + 0] * wi, v[c * 8 + 1] * wi);
        u.y = packbf(v[c * 8 + 2] * wi, v[c * 8 + 3] * wi);
        u.z = packbf(v[c * 8 + 4] * wi, v[c * 8 + 5] * wi);
        u.w = packbf(v[c * 8 + 6] * wi, v[c * 8 + 7] * wi);
        *(uint4*)(dst + ((c ^ (o & 15)) * 16)) = u;
    }
}

// ---------------------------------------------------------------------------
// Kernel B (fast path): MFMA GEMM + max-over-k + partial online-softmax.
// B tiles stream via global_load_lds (16B) into double-buffered LDS; A frags
// (X * xinv, bf16) k-invariant in registers. One barrier per k.
__global__ __launch_bounds__(256, 2) void gemm_mx(
    const float* __restrict__ X, const unsigned char* __restrict__ Wbf,
    const int* __restrict__ label, const float* __restrict__ xinv,
    float2* __restrict__ partial, float* __restrict__ cosl) {

    __shared__ short lds[32768];   // 64 KB: two 32 KB B buffers; X tile overlaid

    const int tid  = threadIdx.x;
    const int lane = tid & 63;
    const int w    = tid >> 6;
    const int l15  = lane & 15;
    const int q    = lane >> 4;
    const int wm   = w & 1;
    const int wn   = w >> 1;

    // XCD-aware decode: ids {group*64 + y*8 + xcd} -> jb = group*8+xcd
    const int id    = blockIdx.x;
    const int group = id >> 6;
    const int sub   = id & 63;
    const int jb    = group * 8 + (sub & 7);
    const int y     = sub >> 3;
    if (jb >= NBLK) return;
    const int r0 = y * 128;
    const int o0 = jb * 128;

    // ---- stage X tile as bf16 with xinv folded ----
    short* xs = lds;
    #pragma unroll
    for (int it = 0; it < 16; it++) {
        int idx = it * 256 + tid;
        int row = idx >> 5;
        int c4  = idx & 31;
        const float4 v = *(const float4*)(X + (size_t)(r0 + row) * FIN + c4 * 4);
        float xi = xinv[r0 + row];
        uint2 p;
        p.x = packbf(v.x * xi, v.y * xi);
        p.y = packbf(v.z * xi, v.w * xi);
        *(uint2*)(xs + row * LDX + c4 * 4) = p;
    }
    __syncthreads();

    short8 af[4][4];
    #pragma unroll
    for (int mt = 0; mt < 4; mt++)
        #pragma unroll
        for (int kk = 0; kk < 4; kk++)
            af[mt][kk] = *(const short8*)(xs + (wm * 64 + mt * 16 + l15) * LDX + kk * 32 + q * 8);
    __syncthreads();   // X area now reusable as B buffers

    // issue B loads for k=0 into buffer 0
    {
        const unsigned char* g = Wbf + ((size_t)0 * OPAD + o0 + w * 32) * 256 + lane * 16;
        short* d = lds + 0 + w * 4096;
        #pragma unroll
        for (int i = 0; i < 8; i++) async16(g + i * 1024, d + i * 512);
    }

    floatx4 maxv[4][4];
    #pragma unroll
    for (int mt = 0; mt < 4; mt++)
        #pragma unroll
        for (int nt = 0; nt < 4; nt++)
            #pragma unroll
            for (int r = 0; r < 4; r++)
                maxv[mt][nt][r] = -INFINITY;

    for (int k = 0; k < NK; k++) {
        __syncthreads();   // drains vmcnt: loads(k) are in LDS; prior reads done
        if (k < NK - 1) {
            const unsigned char* g =
                Wbf + ((size_t)(k + 1) * OPAD + o0 + w * 32) * 256 + lane * 16;
            short* d = lds + ((k + 1) & 1) * 16384 + w * 4096;
            #pragma unroll
            for (int i = 0; i < 8; i++) async16(g + i * 1024, d + i * 512);
        }
        const short* wt = lds + (k & 1) * 16384;

        #pragma unroll
        for (int h = 0; h < 2; h++) {
            floatx4 acc[4][2];
            #pragma unroll
            for (int mt = 0; mt < 4; mt++) {
                acc[mt][0] = (floatx4){0.f, 0.f, 0.f, 0.f};
                acc[mt][1] = (floatx4){0.f, 0.f, 0.f, 0.f};
            }
            #pragma unroll
            for (int kk = 0; kk < 4; kk++) {
                short8 bf[2];
                #pragma unroll
                for (int n2 = 0; n2 < 2; n2++) {
                    int col = wn * 64 + (h * 2 + n2) * 16 + l15;
                    int chunk = (kk * 4 + q) ^ l15;   // un-swizzle
                    bf[n2] = *(const short8*)(wt + col * 128 + chunk * 8);
                }
                #pragma unroll
                for (int mt = 0; mt < 4; mt++) {
                    acc[mt][0] = __builtin_amdgcn_mfma_f32_16x16x32_bf16(af[mt][kk], bf[0], acc[mt][0], 0, 0, 0);
                    acc[mt][1] = __builtin_amdgcn_mfma_f32_16x16x32_bf16(af[mt][kk], bf[1], acc[mt][1], 0, 0, 0);
                }
            }
            #pragma unroll
            for (int mt = 0; mt < 4; mt++)
                #pragma unroll
                for (int n2 = 0; n2 < 2; n2++)
                    #pragma unroll
                    for (int r = 0; r < 4; r++)
                        maxv[mt][h * 2 + n2][r] = fmaxf(maxv[mt][h * 2 + n2][r], acc[mt][n2][r]);
        }
    }

    // ---- epilogue: per-row partial online-softmax (label col excluded) ----
    #pragma unroll
    for (int mt = 0; mt < 4; mt++) {
        #pragma unroll
        for (int rr = 0; rr < 4; rr++) {
            int row = r0 + wm * 64 + mt * 16 + q * 4 + rr;
            int lb = label[row];
            float m = -1e30f, s = 0.f;
            #pragma unroll
            for (int nt = 0; nt < 4; nt++) {
                int o = o0 + wn * 64 + nt * 16 + l15;
                if (o < NOUT) {
                    float c = maxv[mt][nt][rr];   // already cos (norms folded)
                    if (o == lb) {
                        cosl[row] = c;
                    } else {
                        float l = 64.0f * fminf(fmaxf(c, -1.0f + 1e-6f), 1.0f - 1e-6f);
                        if (l > m) { s = s * __expf(m - l) + 1.0f; m = l; }
                        else       { s += __expf(l - m); }
                    }
                }
            }
            #pragma unroll
            for (int off = 1; off <= 8; off <<= 1) {
                float m2 = __shfl_xor(m, off);
                float s2 = __shfl_xor(s, off);
                float M = fmaxf(m, m2);
                s = s * __expf(m - M) + s2 * __expf(m2 - M);
                m = M;
            }
            if (l15 == 0) partial[(size_t)row * NPART + jb * 2 + wn] = make_float2(m, s);
        }
    }
}

// ---------------------------------------------------------------------------
// Fallback GEMM (round-3 path) used when ws_size can't hold Wbf.
__global__ __launch_bounds__(256, 2) void gemm_stats(
    const float* __restrict__ X, const float* __restrict__ W,
    const int* __restrict__ label, const float* __restrict__ xinv,
    float2* __restrict__ partial, float* __restrict__ cosl) {

    __shared__ short xs[128 * LDX];
    __shared__ short wt[128 * LDX];
    __shared__ float sqs[128][2];

    const int tid  = threadIdx.x;
    const int lane = tid & 63;
    const int w    = tid >> 6;
    const int l15  = lane & 15;
    const int q    = lane >> 4;
    const int wm   = w & 1;
    const int wn   = w >> 1;

    const int id    = blockIdx.x;
    const int group = id >> 6;
    const int sub   = id & 63;
    const int jb    = group * 8 + (sub & 7);
    const int y     = sub >> 3;
    if (jb >= NBLK) return;
    const int r0 = y * 128;
    const int o0 = jb * 128;

    #pragma unroll
    for (int it = 0; it < 16; it++) {
        int idx = it * 256 + tid;
        int row = idx >> 5;
        int c4  = idx & 31;
        const float4 v = *(const float4*)(X + (size_t)(r0 + row) * FIN + c4 * 4);
        uint2 p;
        p.x = packbf(v.x, v.y);
        p.y = packbf(v.z, v.w);
        *(uint2*)(xs + row * LDX + c4 * 4) = p;
    }

    const int st_o = (w & 1) * 64 + lane;
    const int st_f = (w >> 1) * 64;
    const int st_h = w >> 1;
    const int go   = o0 + st_o;
    const bool ov  = go < NOUT;

    float rw[64];
    {
        const float* Wp = W + (size_t)st_f * NOUT + go;
        #pragma unroll
        for (int g = 0; g < 16; g++)
            #pragma unroll
            for (int c = 0; c < 4; c++)
                rw[g * 4 + c] = ov ? Wp[(size_t)(g * 4 + c) * NOUT] : 0.0f;
    }
    __syncthreads();

    short8 af[4][4];
    #pragma unroll
    for (int mt = 0; mt < 4; mt++)
        #pragma unroll
        for (int kk = 0; kk < 4; kk++)
            af[mt][kk] = *(const short8*)(xs + (wm * 64 + mt * 16 + l15) * LDX + kk * 32 + q * 8);

    floatx4 maxv[4][4];
    #pragma unroll
    for (int mt = 0; mt < 4; mt++)
        #pragma unroll
        for (int nt = 0; nt < 4; nt++)
            #pragma unroll
            for (int r = 0; r < 4; r++)
                maxv[mt][nt][r] = -INFINITY;

    for (int k = 0; k < NK; k++) {
        float sq = 0.0f;
        uint2 pk[16];
        #pragma unroll
        for (int g = 0; g < 16; g++) {
            float a0 = rw[g * 4 + 0], a1 = rw[g * 4 + 1];
            float a2 = rw[g * 4 + 2], a3 = rw[g * 4 + 3];
            sq = fmaf(a0, a0, sq); sq = fmaf(a1, a1, sq);
            sq = fmaf(a2, a2, sq); sq = fmaf(a3, a3, sq);
            pk[g].x = packbf(a0, a1);
            pk[g].y = packbf(a2, a3);
        }
        __syncthreads();
        #pragma unroll
        for (int g = 0; g < 16; g++)
            *(uint2*)(wt + st_o * LDX + st_f + g * 4) = pk[g];
        sqs[st_o][st_h] = sq;
        __syncthreads();

        if (k < NK - 1) {
            const float* Wn = W + ((size_t)(k + 1) * FIN + st_f) * NOUT + go;
            #pragma unroll
            for (int g = 0; g < 16; g++)
                #pragma unroll
                for (int c = 0; c < 4; c++)
                    rw[g * 4 + c] = ov ? Wn[(size_t)(g * 4 + c) * NOUT] : 0.0f;
        }

        float wv[4];
        #pragma unroll
        for (int nt = 0; nt < 4; nt++) {
            int col = wn * 64 + nt * 16 + l15;
            wv[nt] = 1.0f / fmaxf(sqrtf(sqs[col][0] + sqs[col][1]), 1e-12f);
        }

        #pragma unroll
        for (int h = 0; h < 2; h++) {
            floatx4 acc[4][2];
            #pragma unroll
            for (int mt = 0; mt < 4; mt++) {
                acc[mt][0] = (floatx4){0.f, 0.f, 0.f, 0.f};
                acc[mt][1] = (floatx4){0.f, 0.f, 0.f, 0.f};
            }
            #pragma unroll
            for (int kk = 0; kk < 4; kk++) {
                short8 bf0 = *(const short8*)(wt + (wn * 64 + (h * 2 + 0) * 16 + l15) * LDX + kk * 32 + q * 8);
                short8 bf1 = *(const short8*)(wt + (wn * 64 + (h * 2 + 1) * 16 + l15) * LDX + kk * 32 + q * 8);
                #pragma unroll
                for (int mt = 0; mt < 4; mt++) {
                    acc[mt][0] = __builtin_amdgcn_mfma_f32_16x16x32_bf16(af[mt][kk], bf0, acc[mt][0], 0, 0, 0);
                    acc[mt][1] = __builtin_amdgcn_mfma_f32_16x16x32_bf16(af[mt][kk], bf1, acc[mt][1], 0, 0, 0);
                }
            }
            #pragma unroll
            for (int mt = 0; mt < 4; mt++)
                #pragma unroll
                for (int n2 = 0; n2 < 2; n2++)
                    #pragma unroll
                    for (int r = 0; r < 4; r++)
                        maxv[mt][h * 2 + n2][r] =
                            fmaxf(maxv[mt][h * 2 + n2][r], acc[mt][n2][r] * wv[h * 2 + n2]);
        }
    }

    #pragma unroll
    for (int mt = 0; mt < 4; mt++) {
        #pragma unroll
        for (int rr = 0; rr < 4; rr++) {
            int row = r0 + wm * 64 + mt * 16 + q * 4 + rr;
            float xi = xinv[row];
            int lb = label[row];
            float m = -1e30f, s = 0.f;
            #pragma unroll
            for (int nt = 0; nt < 4; nt++) {
                int o = o0 + wn * 64 + nt * 16 + l15;
                if (o < NOUT) {
                    float c = maxv[mt][nt][rr] * xi;
                    if (o == lb) {
                        cosl[row] = c;
                    } else {
                        float l = 64.0f * fminf(fmaxf(c, -1.0f + 1e-6f), 1.0f - 1e-6f);
                        if (l > m) { s = s * __expf(m - l) + 1.0f; m = l; }
                        else       { s += __expf(l - m); }
                    }
                }
            }
            #pragma unroll
            for (int off = 1; off <= 8; off <<= 1) {
                float m2 = __shfl_xor(m, off);
                float s2 = __shfl_xor(s, off);
                float M = fmaxf(m, m2);
                s = s * __expf(m - M) + s2 * __expf(m2 - M);
                m = M;
            }
            if (l15 == 0) partial[(size_t)row * NPART + jb * 2 + wn] = make_float2(m, s);
        }
    }
}

// ---------------------------------------------------------------------------
// Kernel C1: per-row combine + margin -> (loss, corr) per row. No atomics.
__global__ void finalize_rows(const float2* __restrict__ partial, const float* __restrict__ cosl,
                              const float* __restrict__ fa, const float* __restrict__ thr,
                              float2* __restrict__ rowres) {
    int w = threadIdx.x >> 6;
    int lane = threadIdx.x & 63;
    int b = blockIdx.x * 4 + w;
    float m = -1e30f, s = 0.0f;
    for (int j = lane; j < NPART; j += 64) {
        float2 p = partial[(size_t)b * NPART + j];
        float M = fmaxf(m, p.x);
        s = s * __expf(m - M) + p.y * __expf(p.x - M);
        m = M;
    }
    #pragma unroll
    for (int off = 1; off < 64; off <<= 1) {
        float m2 = __shfl_xor(m, off);
        float s2 = __shfl_xor(s, off);
        float M = fmaxf(m, m2);
        s = s * __expf(m - M) + s2 * __expf(m2 - M);
        m = M;
    }
    if (lane == 0) {
        float c = fminf(fmaxf(cosl[b], -1.0f + 1e-6f), 1.0f - 1e-6f);
        float theta = acosf(c);
        float ll = (theta > thr[b]) ? 64.0f * c : 64.0f * cosf(theta + fa[b]);
        float M = fmaxf(m, ll);
        float S = s * __expf(m - M) + __expf(ll - M);
        rowres[b] = make_float2(M + logf(S) - ll, (ll > m) ? 100.0f : 0.0f);
    }
}

// Kernel C2: deterministic tree reduce of 1024 rows -> 2 scalars.
__global__ void finalize_sum(const float2* __restrict__ rowres, float* __restrict__ out) {
    __shared__ float sl[1024];
    __shared__ float sc[1024];
    int b = threadIdx.x;
    float2 v = rowres[b];
    sl[b] = v.x;
    sc[b] = v.y;
    __syncthreads();
    for (int st = 512; st > 0; st >>= 1) {
        if (b < st) { sl[b] += sl[b + st]; sc[b] += sc[b + st]; }
        __syncthreads();
    }
    if (b == 0) {
        out[0] = sl[0] * (1.0f / 1024.0f);
        out[1] = sc[0] * (1.0f / 1024.0f);
    }
}

// ---------------------------------------------------------------------------
extern "C" void kernel_launch(void* const* d_in, const int* in_sizes, int n_in,
                              void* d_out, int out_size, void* d_ws, size_t ws_size,
                              hipStream_t stream) {
    const float* X      = (const float*)d_in[0];
    const float* factor = (const float*)d_in[1];
    const int*   label  = (const int*)d_in[2];
    const float* W      = (const float*)d_in[3];
    float* out = (float*)d_out;
    float* ws  = (float*)d_ws;

    float*  xinv = ws;                        // 1024
    float*  fa   = ws + 1024;                 // 1024
    float*  thr  = ws + 2048;                 // 1024
    float*  cosl = ws + 3072;                 // 1024
    float2* rowres = (float2*)(ws + 4096);    // 1024 float2
    float2* partial = (float2*)(ws + 6144);   // 1024 x NPART float2
    unsigned char* Wbf = (unsigned char*)d_ws + 2 * 1024 * 1024;  // 41.4 MB

    const size_t need = 2ull * 1024 * 1024 + (size_t)NK * OPAD * 256;

    rowprep<<<BB, 64, 0, stream>>>(X, factor, xinv, fa, thr);
    if (ws_size >= need) {
        wconv<<<(NK * OPAD) / 256, 256, 0, stream>>>(W, Wbf);
        gemm_mx<<<640, 256, 0, stream>>>(X, Wbf, label, xinv, partial, cosl);
    } else {
        gemm_stats<<<640, 256, 0, stream>>>(X, W, label, xinv, partial, cosl);
    }
    finalize_rows<<<BB / 4, 256, 0, stream>>>(partial, cosl, fa, thr, rowres);
    finalize_sum<<<1, BB, 0, stream>>>(rowres, out);
}